// Round 1
// baseline (240.952 us; speedup 1.0000x reference)
//
#include <hip/hip_runtime.h>
#include <hip/hip_bf16.h>

#define WAVES_PER_BLOCK 4
#define BLOCK (WAVES_PER_BLOCK * 64)
#define TOTAL_WAVES 4096

__device__ __forceinline__ float wave_sum(float v) {
#pragma unroll
    for (int m = 32; m >= 1; m >>= 1) v += __shfl_xor(v, m, 64);
    return v;
}

__global__ __launch_bounds__(BLOCK) void vecout_kernel(
    const float* __restrict__ atom_out,   // [N,480]
    const float* __restrict__ ln_w,       // [224], we use 128..191
    const float* __restrict__ W1_1,       // [64,64] row-major [u][v]
    const float* __restrict__ W2,         // [64,1]
    const int*   __restrict__ batch_idx,  // [N], sorted
    float* __restrict__ out,              // [B,3]
    int N, int chunk)
{
    __shared__ float fsh[WAVES_PER_BLOCK][192];
    const int lane = threadIdx.x & 63;
    const int wid  = threadIdx.x >> 6;
    const int gw   = blockIdx.x * WAVES_PER_BLOCK + wid;
    const int a0   = gw * chunk;
    if (a0 >= N) return;                 // no barriers used -> safe early-out
    const int a1   = min(N, a0 + chunk);

    // Lane v holds column v of W1_1 (64 VGPRs), reused for every atom.
    float Wc[64];
#pragma unroll
    for (int u = 0; u < 64; ++u) Wc[u] = W1_1[u * 64 + lane];
    const float w2v = W2[lane] * 0.125f;          // fold 1/sqrt(64) of 2nd linear

    // This lane stages flat elements k, k+64, k+128 of the 192-elem 1e field.
    const int k0 = lane, k1 = lane + 64, k2 = lane + 128;
    const float lw0 = ln_w[128 + k0 / 3];
    const float lw1 = ln_w[128 + k1 / 3];
    const float lw2 = ln_w[128 + k2 / 3];

    float* fs = fsh[wid];

    float s0 = 0.f, s1 = 0.f, s2 = 0.f;          // running per-batch accum (per lane)
    int cur_b = batch_idx[a0];

    // prefetch first atom
    const float* row = atom_out + (long long)a0 * 480 + 128;
    float f0 = row[k0], f1 = row[k1], f2 = row[k2];
    int   b_cur = cur_b;

    for (int a = a0; a < a1; ++a) {
        // ---- prefetch next atom (hide HBM latency under compute) ----
        float nf0 = 0.f, nf1 = 0.f, nf2 = 0.f;
        int   nb = b_cur;
        if (a + 1 < a1) {
            const float* nrow = atom_out + (long long)(a + 1) * 480 + 128;
            nf0 = nrow[k0]; nf1 = nrow[k1]; nf2 = nrow[k2];
            nb  = batch_idx[a + 1];
        }

        // ---- segment flush on batch change (batch_idx sorted -> rare) ----
        if (b_cur != cur_b) {
            float t0 = wave_sum(s0), t1 = wave_sum(s1), t2 = wave_sum(s2);
            if (lane == 0) {
                // e3nn (y,z,x)->(x,y,z): out0=vec2, out1=vec0, out2=vec1
                atomicAdd(&out[cur_b * 3 + 0], t2);
                atomicAdd(&out[cur_b * 3 + 1], t0);
                atomicAdd(&out[cur_b * 3 + 2], t1);
            }
            s0 = s1 = s2 = 0.f;
            cur_b = b_cur;
        }

        // ---- equivariant RMS norm over the 1e field ----
        float nrm = f0 * f0 + f1 * f1 + f2 * f2;
        nrm = wave_sum(nrm);                              // sum over all 192 elems
        // norm2 = sum/64 ; inv = rsqrt(norm2+eps) ; fold 1/sqrt(64) of linear1
        float inv = rsqrtf(nrm * (1.0f / 64.0f) + 1e-5f) * 0.125f;

        fs[k0] = f0 * inv * lw0;
        fs[k1] = f1 * inv * lw1;
        fs[k2] = f2 * inv * lw2;
        __builtin_amdgcn_wave_barrier();   // wave-synchronous LDS: order write->read

        // ---- matvec: g[v][i] = sum_u fhat[u][i] * W[u][v]  (broadcast reads) ----
        float g0 = 0.f, g1 = 0.f, g2 = 0.f;
        const float4* fs4 = (const float4*)fs;
#pragma unroll
        for (int m = 0; m < 16; ++m) {
            float4 A = fs4[3 * m], B = fs4[3 * m + 1], C = fs4[3 * m + 2];
            int u = 4 * m;
            g0 += A.x * Wc[u];     g1 += A.y * Wc[u];     g2 += A.z * Wc[u];
            g0 += A.w * Wc[u + 1]; g1 += B.x * Wc[u + 1]; g2 += B.y * Wc[u + 1];
            g0 += B.z * Wc[u + 2]; g1 += B.w * Wc[u + 2]; g2 += C.x * Wc[u + 2];
            g0 += C.y * Wc[u + 3]; g1 += C.z * Wc[u + 3]; g2 += C.w * Wc[u + 3];
        }

        // ---- gate: sigmoid(|g|) ----
        float q  = g0 * g0 + g1 * g1 + g2 * g2;
        float nr = sqrtf(q + 1e-12f);
        float sg = 1.0f / (1.0f + __expf(-nr));

        // ---- second linear (per-lane partial, reduced lazily at flush) ----
        float t = sg * w2v;
        s0 += g0 * t; s1 += g1 * t; s2 += g2 * t;

        // rotate prefetch
        f0 = nf0; f1 = nf1; f2 = nf2; b_cur = nb;
    }

    // final flush
    {
        float t0 = wave_sum(s0), t1 = wave_sum(s1), t2 = wave_sum(s2);
        if (lane == 0) {
            atomicAdd(&out[cur_b * 3 + 0], t2);
            atomicAdd(&out[cur_b * 3 + 1], t0);
            atomicAdd(&out[cur_b * 3 + 2], t1);
        }
    }
}

extern "C" void kernel_launch(void* const* d_in, const int* in_sizes, int n_in,
                              void* d_out, int out_size, void* d_ws, size_t ws_size,
                              hipStream_t stream) {
    const float* atom_out  = (const float*)d_in[0];
    const float* ln_w      = (const float*)d_in[2];
    const float* W1_1      = (const float*)d_in[5];
    const float* W2        = (const float*)d_in[7];
    const int*   batch_idx = (const int*)d_in[9];
    float* out = (float*)d_out;

    const int N = in_sizes[0] / 480;

    hipMemsetAsync(d_out, 0, (size_t)out_size * sizeof(float), stream);

    const int chunk = (N + TOTAL_WAVES - 1) / TOTAL_WAVES;
    vecout_kernel<<<TOTAL_WAVES / WAVES_PER_BLOCK, BLOCK, 0, stream>>>(
        atom_out, ln_w, W1_1, W2, batch_idx, out, N, chunk);
}

// Round 2
// 89.229 us; speedup vs baseline: 2.7004x; 2.7004x over previous
//
#include <hip/hip_runtime.h>
#include <hip/hip_bf16.h>

#define WPB 4                 // waves per block
#define BLOCK (WPB * 64)
#define GPW 5                 // 16-atom groups per wave
#define APW (GPW * 16)        // atoms per wave

typedef __attribute__((ext_vector_type(8))) short s16x8;   // 8 bf16 (4 VGPRs)
typedef __attribute__((ext_vector_type(4))) float f32x4;   // MFMA accumulator

__device__ __forceinline__ float wave_sum64(float v) {
#pragma unroll
    for (int m = 32; m >= 1; m >>= 1) v += __shfl_xor(v, m, 64);
    return v;
}

__device__ __forceinline__ short bf16b(float x) {          // f32 -> bf16 (RNE)
    union { float f; unsigned u; } c; c.f = x;
    unsigned r = c.u + 0x7FFFu + ((c.u >> 16) & 1u);
    return (short)(r >> 16);
}

__global__ __launch_bounds__(BLOCK) void vecout_mfma(
    const float* __restrict__ atom_out,   // [N,480]; 1e block = cols 128..319
    const float* __restrict__ ln_w,       // [224]; 1e weights at 128..191
    const float* __restrict__ W1_1,       // [64,64] row-major [u][v]
    const float* __restrict__ W2,         // [64]
    const int*   __restrict__ batch_idx,  // [N], sorted
    float* __restrict__ out,              // [B,3]
    int N)
{
    __shared__ __align__(16) short Ash[WPB][48 * 64];  // [c][atom][u] bf16, swizzled
    __shared__ float invsh[WPB][16];

    const int lane = threadIdx.x & 63;
    const int wid  = threadIdx.x >> 6;
    const int gw   = blockIdx.x * WPB + wid;
    const int a0   = gw * APW;
    if (a0 >= N) return;                  // no block barriers -> safe early-out

    const int col  = lane & 15;           // B col / C col / v-within-tile
    const int kgrp = lane >> 4;           // k-group for A/B frags
    const int atomi = lane & 15;          // A row (atom-local)
    const unsigned swz = (unsigned)(lane & 7) << 4;   // LDS XOR swizzle (16B units)

    // ---- B fragments: W'[k][v] = W1_1[k][v] * ln_w[128+k] * (1/sqrt(64)), bf16 ----
    s16x8 Bf[2][4];
#pragma unroll
    for (int kt = 0; kt < 2; ++kt)
#pragma unroll
        for (int nt = 0; nt < 4; ++nt) {
            s16x8 b;
#pragma unroll
            for (int j = 0; j < 8; ++j) {
                int k = kt * 32 + kgrp * 8 + j;
                float w = W1_1[k * 64 + nt * 16 + col] * ln_w[128 + k] * 0.125f;
                b[j] = bf16b(w);
            }
            Bf[kt][nt] = b;
        }
    float w2r[4];
#pragma unroll
    for (int nt = 0; nt < 4; ++nt) w2r[nt] = W2[nt * 16 + col] * 0.125f;

    char* Ab = (char*)(&Ash[wid][0]);

    float acc[4][3];                       // deferred per-batch accum [reg][comp]
#pragma unroll
    for (int r = 0; r < 4; ++r) { acc[r][0] = 0.f; acc[r][1] = 0.f; acc[r][2] = 0.f; }
    int accb = batch_idx[a0];

    auto flushAcc = [&]() {
        float s0 = acc[0][0] + acc[1][0] + acc[2][0] + acc[3][0];
        float s1 = acc[0][1] + acc[1][1] + acc[2][1] + acc[3][1];
        float s2 = acc[0][2] + acc[1][2] + acc[2][2] + acc[3][2];
        s0 = wave_sum64(s0); s1 = wave_sum64(s1); s2 = wave_sum64(s2);
        if (lane == 0) {
            // e3nn (y,z,x) -> (x,y,z): out0=c2, out1=c0, out2=c1
            atomicAdd(&out[accb * 3 + 0], s2);
            atomicAdd(&out[accb * 3 + 1], s0);
            atomicAdd(&out[accb * 3 + 2], s1);
        }
#pragma unroll
        for (int r = 0; r < 4; ++r) { acc[r][0] = 0.f; acc[r][1] = 0.f; acc[r][2] = 0.f; }
    };

    for (int g = 0; g < GPW; ++g) {
        int a = a0 + g * 16;
        if (a >= N) break;
        int myatom = a + atomi;
        bool valid = myatom < N;

        // ---- load: lane holds elems e = kgrp*48 + [0..47] of atom (lane&15) ----
        float R[48];
        {
            const float4* p = reinterpret_cast<const float4*>(
                atom_out + (size_t)myatom * 480 + 128 + kgrp * 48);
#pragma unroll
            for (int j = 0; j < 12; ++j) {
                float4 t = valid ? p[j] : make_float4(0.f, 0.f, 0.f, 0.f);
                R[4 * j + 0] = t.x; R[4 * j + 1] = t.y;
                R[4 * j + 2] = t.z; R[4 * j + 3] = t.w;
            }
        }

        // ---- per-atom RMS norm (4 lanes/atom share via 2 shfls) ----
        float nrm = 0.f;
#pragma unroll
        for (int m = 0; m < 48; ++m) nrm += R[m] * R[m];
        nrm += __shfl_xor(nrm, 16, 64);
        nrm += __shfl_xor(nrm, 32, 64);
        float inv = rsqrtf(nrm * (1.0f / 64.0f) + 1e-5f);
        if (lane < 16) invsh[wid][lane] = inv;

        // ---- stage A: [c][atom][u] bf16, XOR-swizzled, b128 writes ----
        // lane's elems: u = kgrp*16 + j, comp c at R[3*j + c]
#pragma unroll
        for (int c = 0; c < 3; ++c) {
            s16x8 P0, P1;
#pragma unroll
            for (int j = 0; j < 8; ++j) P0[j] = bf16b(R[3 * j + c]);
#pragma unroll
            for (int j = 0; j < 8; ++j) P1[j] = bf16b(R[3 * (j + 8) + c]);
            unsigned rr = (unsigned)(c * 16 + atomi) * 128u;
            unsigned ub = (unsigned)kgrp * 32u;
            *(s16x8*)(Ab + rr + (ub ^ swz))         = P0;
            *(s16x8*)(Ab + rr + ((ub + 16u) ^ swz)) = P1;
        }
        asm volatile("s_waitcnt lgkmcnt(0)" ::: "memory");

        // ---- A fragment reads: lane = row (atom), 8 consecutive u ----
        s16x8 Af[3][2];
#pragma unroll
        for (int c = 0; c < 3; ++c)
#pragma unroll
            for (int kt = 0; kt < 2; ++kt) {
                unsigned rr = (unsigned)(c * 16 + atomi) * 128u;
                unsigned ub = (unsigned)(kt * 64 + kgrp * 16);
                Af[c][kt] = *(const s16x8*)(Ab + rr + (ub ^ swz));
            }

        // ---- MFMA: D[atom][v] = sum_u f[atom][u][c] * W'[u][v], 3 c-tiles x 4 v-tiles ----
        f32x4 Cf[3][4];
#pragma unroll
        for (int c = 0; c < 3; ++c)
#pragma unroll
            for (int nt = 0; nt < 4; ++nt) {
                f32x4 z = {0.f, 0.f, 0.f, 0.f};
                z = __builtin_amdgcn_mfma_f32_16x16x32_bf16(Af[c][0], Bf[0][nt], z, 0, 0, 0);
                z = __builtin_amdgcn_mfma_f32_16x16x32_bf16(Af[c][1], Bf[1][nt], z, 0, 0, 0);
                Cf[c][nt] = z;
            }

        // ---- epilogue: gate + W2, all 3 comps of (atom,v) live in same lane/reg ----
        float invA[4];
#pragma unroll
        for (int r = 0; r < 4; ++r) invA[r] = invsh[wid][kgrp * 4 + r];

        float part[4][3];
#pragma unroll
        for (int r = 0; r < 4; ++r) {
            part[r][0] = 0.f; part[r][1] = 0.f; part[r][2] = 0.f;
            float iv = invA[r];
#pragma unroll
            for (int nt = 0; nt < 4; ++nt) {
                float g0 = Cf[0][nt][r] * iv;
                float g1 = Cf[1][nt][r] * iv;
                float g2 = Cf[2][nt][r] * iv;
                float q  = g0 * g0 + g1 * g1 + g2 * g2;
                float nr = sqrtf(q + 1e-12f);
                float sg = 1.f / (1.f + __expf(-nr));
                float t  = sg * w2r[nt];
                part[r][0] += g0 * t; part[r][1] += g1 * t; part[r][2] += g2 * t;
            }
        }

        // ---- segment accumulation (batch_idx sorted) ----
        int bfst = batch_idx[a];
        int blst = batch_idx[min(a + 15, N - 1)];
        if (bfst == blst) {
            if (bfst != accb) { flushAcc(); accb = bfst; }
#pragma unroll
            for (int r = 0; r < 4; ++r) {
                acc[r][0] += part[r][0]; acc[r][1] += part[r][1]; acc[r][2] += part[r][2];
            }
        } else {
            // rare boundary group: flush, then per-atom direct adds
            flushAcc();
#pragma unroll
            for (int r = 0; r < 4; ++r) {
                float c0 = part[r][0], c1 = part[r][1], c2 = part[r][2];
#pragma unroll
                for (int m = 1; m < 16; m <<= 1) {
                    c0 += __shfl_xor(c0, m, 64);
                    c1 += __shfl_xor(c1, m, 64);
                    c2 += __shfl_xor(c2, m, 64);
                }
                int ai = a + kgrp * 4 + r;       // C row = atom-local index
                if (col == 0 && ai < N) {
                    int b = batch_idx[ai];
                    atomicAdd(&out[b * 3 + 0], c2);
                    atomicAdd(&out[b * 3 + 1], c0);
                    atomicAdd(&out[b * 3 + 2], c1);
                }
            }
            accb = blst;
        }
    }

    flushAcc();
}

extern "C" void kernel_launch(void* const* d_in, const int* in_sizes, int n_in,
                              void* d_out, int out_size, void* d_ws, size_t ws_size,
                              hipStream_t stream) {
    const float* atom_out  = (const float*)d_in[0];
    const float* ln_w      = (const float*)d_in[2];
    const float* W1_1      = (const float*)d_in[5];
    const float* W2        = (const float*)d_in[7];
    const int*   batch_idx = (const int*)d_in[9];
    float* out = (float*)d_out;

    const int N = in_sizes[0] / 480;

    hipMemsetAsync(d_out, 0, (size_t)out_size * sizeof(float), stream);

    const int waves  = (N + APW - 1) / APW;
    const int blocks = (waves + WPB - 1) / WPB;
    vecout_mfma<<<blocks, BLOCK, 0, stream>>>(atom_out, ln_w, W1_1, W2, batch_idx, out, N);
}

// Round 3
// 68.004 us; speedup vs baseline: 3.5432x; 1.3121x over previous
//
#include <hip/hip_runtime.h>
#include <hip/hip_bf16.h>

#define WPB 4                 // waves per block
#define BLOCK (WPB * 64)
#define GRID 512              // 2 blocks/CU x 256 CU -> fully resident, no tail

typedef __attribute__((ext_vector_type(8))) short s16x8;   // 8 bf16 (4 VGPRs)
typedef __attribute__((ext_vector_type(4))) float f32x4;   // MFMA accumulator

__device__ __forceinline__ float wave_sum64(float v) {
#pragma unroll
    for (int m = 32; m >= 1; m >>= 1) v += __shfl_xor(v, m, 64);
    return v;
}

__device__ __forceinline__ short bf16b(float x) {          // f32 -> bf16 (RNE)
    union { float f; unsigned u; } c; c.f = x;
    unsigned r = c.u + 0x7FFFu + ((c.u >> 16) & 1u);
    return (short)(r >> 16);
}

__global__ __launch_bounds__(BLOCK, 2) void vecout_mfma(
    const float* __restrict__ atom_out,   // [N,480]; 1e block = cols 128..319
    const float* __restrict__ ln_w,       // [224]; 1e weights at 128..191
    const float* __restrict__ W1_1,       // [64,64] row-major [u][v]
    const float* __restrict__ W2,         // [64]
    const int*   __restrict__ batch_idx,  // [N], sorted
    float* __restrict__ out,              // [B,3]
    int N)
{
    __shared__ __align__(16) short Ash[WPB][48 * 64];  // [c*16+atom][u] bf16, swizzled
    __shared__ float invsh[WPB][16];

    const int lane  = threadIdx.x & 63;
    const int wid   = threadIdx.x >> 6;
    const int col   = lane & 15;          // B col / C col (v within tile)
    const int kgrp  = lane >> 4;          // k-group for A/B frags
    const int atomi = lane & 15;          // A row (atom-local)
    const unsigned swz = (unsigned)(lane & 7) << 4;   // LDS XOR swizzle (16B units)

    // ---- balanced contiguous group partition across all waves ----
    const int NG = (N + 15) >> 4;                 // 16-atom groups
    const int NW = gridDim.x * WPB;
    const int w  = blockIdx.x * WPB + wid;
    const int cpw = NG / NW, rem = NG % NW;
    const int g0  = w * cpw + min(w, rem);
    const int cnt = cpw + (w < rem ? 1 : 0);
    if (cnt <= 0) return;                          // no block barriers -> safe
    const int gend = g0 + cnt;

    // ---- B fragments: W'[k][v] = W1_1[k][v] * ln_w[128+k] * (1/sqrt(64)) ----
    s16x8 Bf[2][4];
#pragma unroll
    for (int kt = 0; kt < 2; ++kt)
#pragma unroll
        for (int nt = 0; nt < 4; ++nt) {
            s16x8 b;
#pragma unroll
            for (int j = 0; j < 8; ++j) {
                int k = kt * 32 + kgrp * 8 + j;
                float wgt = W1_1[k * 64 + nt * 16 + col] * ln_w[128 + k] * 0.125f;
                b[j] = bf16b(wgt);
            }
            Bf[kt][nt] = b;
        }
    float w2r[4];
#pragma unroll
    for (int nt = 0; nt < 4; ++nt) w2r[nt] = W2[nt * 16 + col] * 0.125f;

    char* Ab = (char*)(&Ash[wid][0]);

    float acc[4][3];
#pragma unroll
    for (int r = 0; r < 4; ++r) { acc[r][0] = 0.f; acc[r][1] = 0.f; acc[r][2] = 0.f; }
    int accb = batch_idx[g0 * 16];

    auto flushAcc = [&]() {
        float s0 = acc[0][0] + acc[1][0] + acc[2][0] + acc[3][0];
        float s1 = acc[0][1] + acc[1][1] + acc[2][1] + acc[3][1];
        float s2 = acc[0][2] + acc[1][2] + acc[2][2] + acc[3][2];
        s0 = wave_sum64(s0); s1 = wave_sum64(s1); s2 = wave_sum64(s2);
        if (lane == 0) {
            // e3nn (y,z,x) -> (x,y,z): out0=c2, out1=c0, out2=c1
            atomicAdd(&out[accb * 3 + 0], s2);
            atomicAdd(&out[accb * 3 + 1], s0);
            atomicAdd(&out[accb * 3 + 2], s1);
        }
#pragma unroll
        for (int r = 0; r < 4; ++r) { acc[r][0] = 0.f; acc[r][1] = 0.f; acc[r][2] = 0.f; }
    };

    // ---- issue 12 coalesced float4 loads for group g into R ----
    auto loadG = [&](float (&R)[48], int g) {
        int myatom = g * 16 + atomi;
        int ma = min(myatom, N - 1);
        const float4* p = reinterpret_cast<const float4*>(
            atom_out + (size_t)ma * 480 + 128 + kgrp * 48);
#pragma unroll
        for (int j = 0; j < 12; ++j) {
            float4 t = p[j];
            R[4 * j + 0] = t.x; R[4 * j + 1] = t.y;
            R[4 * j + 2] = t.z; R[4 * j + 3] = t.w;
        }
    };

    // ---- full per-group compute ----
    auto computeG = [&](const float (&R)[48], int g) {
        int a = g * 16;

        // per-atom RMS norm (4 lanes/atom share via 2 shfls)
        float nrm = 0.f;
#pragma unroll
        for (int m = 0; m < 48; ++m) nrm += R[m] * R[m];
        nrm += __shfl_xor(nrm, 16, 64);
        nrm += __shfl_xor(nrm, 32, 64);
        float inv = rsqrtf(nrm * (1.0f / 64.0f) + 1e-5f);
        if (lane < 16) invsh[wid][lane] = inv;

        // stage A: [c*16+atom][u] bf16, XOR-swizzled, b128 writes
#pragma unroll
        for (int c = 0; c < 3; ++c) {
            s16x8 P0, P1;
#pragma unroll
            for (int j = 0; j < 8; ++j) P0[j] = bf16b(R[3 * j + c]);
#pragma unroll
            for (int j = 0; j < 8; ++j) P1[j] = bf16b(R[3 * (j + 8) + c]);
            unsigned rr = (unsigned)(c * 16 + atomi) * 128u;
            unsigned ub = (unsigned)kgrp * 32u;
            *(s16x8*)(Ab + rr + (ub ^ swz))         = P0;
            *(s16x8*)(Ab + rr + ((ub + 16u) ^ swz)) = P1;
        }
        asm volatile("s_waitcnt lgkmcnt(0)" ::: "memory");

        // A fragment reads: lane = row (atom), 8 consecutive u
        s16x8 Af[3][2];
#pragma unroll
        for (int c = 0; c < 3; ++c)
#pragma unroll
            for (int kt = 0; kt < 2; ++kt) {
                unsigned rr = (unsigned)(c * 16 + atomi) * 128u;
                unsigned ub = (unsigned)(kt * 64 + kgrp * 16);
                Af[c][kt] = *(const s16x8*)(Ab + rr + (ub ^ swz));
            }

        // MFMA: D[atom][v] = sum_u f[atom][u][c] * W'[u][v]
        f32x4 Cf[3][4];
#pragma unroll
        for (int c = 0; c < 3; ++c)
#pragma unroll
            for (int nt = 0; nt < 4; ++nt) {
                f32x4 z = {0.f, 0.f, 0.f, 0.f};
                z = __builtin_amdgcn_mfma_f32_16x16x32_bf16(Af[c][0], Bf[0][nt], z, 0, 0, 0);
                z = __builtin_amdgcn_mfma_f32_16x16x32_bf16(Af[c][1], Bf[1][nt], z, 0, 0, 0);
                Cf[c][nt] = z;
            }

        // epilogue: gate + W2; 3 comps of (atom,v) live in same lane/reg
        float invA[4];
#pragma unroll
        for (int r = 0; r < 4; ++r) invA[r] = invsh[wid][kgrp * 4 + r];

        float part[4][3];
#pragma unroll
        for (int r = 0; r < 4; ++r) {
            part[r][0] = 0.f; part[r][1] = 0.f; part[r][2] = 0.f;
            float iv = invA[r];
#pragma unroll
            for (int nt = 0; nt < 4; ++nt) {
                float g0v = Cf[0][nt][r] * iv;
                float g1v = Cf[1][nt][r] * iv;
                float g2v = Cf[2][nt][r] * iv;
                float q  = g0v * g0v + g1v * g1v + g2v * g2v;
                float nr = sqrtf(q + 1e-12f);
                float sg = 1.f / (1.f + __expf(-nr));
                float t  = sg * w2r[nt];
                part[r][0] += g0v * t; part[r][1] += g1v * t; part[r][2] += g2v * t;
            }
            if (a + kgrp * 4 + r >= N) { part[r][0] = 0.f; part[r][1] = 0.f; part[r][2] = 0.f; }
        }

        // segment accumulation (batch_idx sorted)
        int bfst = batch_idx[a];
        int blst = batch_idx[min(a + 15, N - 1)];
        if (bfst == blst) {
            if (bfst != accb) { flushAcc(); accb = bfst; }
#pragma unroll
            for (int r = 0; r < 4; ++r) {
                acc[r][0] += part[r][0]; acc[r][1] += part[r][1]; acc[r][2] += part[r][2];
            }
        } else {
            flushAcc();
#pragma unroll
            for (int r = 0; r < 4; ++r) {
                float c0 = part[r][0], c1 = part[r][1], c2 = part[r][2];
#pragma unroll
                for (int m = 1; m < 16; m <<= 1) {
                    c0 += __shfl_xor(c0, m, 64);
                    c1 += __shfl_xor(c1, m, 64);
                    c2 += __shfl_xor(c2, m, 64);
                }
                int ai = a + kgrp * 4 + r;
                if (col == 0 && ai < N) {
                    int b = batch_idx[ai];
                    atomicAdd(&out[b * 3 + 0], c2);
                    atomicAdd(&out[b * 3 + 1], c0);
                    atomicAdd(&out[b * 3 + 2], c1);
                }
            }
            accb = blst;
        }
    };

    // ---- 1-deep software pipeline: loads for g+1 in flight during compute of g ----
    float RA[48], RB[48];
    int g = g0;
    loadG(RA, g);
    while (true) {
        int gn = g + 1;
        if (gn < gend) loadG(RB, gn);
        computeG(RA, g);
        if (gn >= gend) break;
        g = gn; gn = g + 1;
        if (gn < gend) loadG(RA, gn);
        computeG(RB, g);
        if (gn >= gend) break;
        g = gn;
    }

    flushAcc();
}

extern "C" void kernel_launch(void* const* d_in, const int* in_sizes, int n_in,
                              void* d_out, int out_size, void* d_ws, size_t ws_size,
                              hipStream_t stream) {
    const float* atom_out  = (const float*)d_in[0];
    const float* ln_w      = (const float*)d_in[2];
    const float* W1_1      = (const float*)d_in[5];
    const float* W2        = (const float*)d_in[7];
    const int*   batch_idx = (const int*)d_in[9];
    float* out = (float*)d_out;

    const int N = in_sizes[0] / 480;

    hipMemsetAsync(d_out, 0, (size_t)out_size * sizeof(float), stream);

    vecout_mfma<<<GRID, BLOCK, 0, stream>>>(atom_out, ln_w, W1_1, W2, batch_idx, out, N);
}